// Round 9
// baseline (464.173 us; speedup 1.0000x reference)
//
#include <hip/hip_runtime.h>

#define ALP 0.1f          // alpha
#define OMA 0.9f          // 1 - alpha
#define D 64
#define DV 16             // float4 chunks per row
#define SH 8              // 256 nodes per bucket
#define BNODES 256
#define OVF_MAX 65536

// ---------- bf16 helpers ----------
__device__ __forceinline__ unsigned short f2b(float f) {      // RNE
    unsigned u = __float_as_uint(f);
    unsigned r = u + 0x7fffu + ((u >> 16) & 1u);
    return (unsigned short)(r >> 16);
}
__device__ __forceinline__ float b2f(unsigned short u) {
    return __uint_as_float(((unsigned)u) << 16);
}

// ---------- msg = bf16(h * aft_A)  + zero gcnt/ovfCnt (block 0) ----------
__global__ void vsgc_msg(const float4* __restrict__ h4, const float* __restrict__ aft_A,
                         ushort4* __restrict__ msgb, int* __restrict__ zeroRegion,
                         int zeroWords, int n16) {
    if (blockIdx.x == 0) {
        for (int j = threadIdx.x; j < zeroWords; j += blockDim.x) zeroRegion[j] = 0;
    }
    int i = blockIdx.x * blockDim.x + threadIdx.x;
    if (i >= n16) return;
    float w = aft_A[i >> 4];
    float4 v = h4[i];
    msgb[i] = make_ushort4(f2b(v.x * w), f2b(v.y * w), f2b(v.z * w), f2b(v.w * w));
}

// ---------- pass 1: bucket scatter, packed 4B records (src<<8 | local) ----------
__global__ __launch_bounds__(256) void p1_scatter(const int4* __restrict__ src4,
                                                  const int4* __restrict__ dst4,
                                                  int* __restrict__ gcnt,
                                                  int* __restrict__ buckets,
                                                  int2* __restrict__ ovf,
                                                  int* __restrict__ ovfCnt,
                                                  int E, int NB, int BCAP) {
    __shared__ int cnt[512], gbase[512], pos[512];
    int tid = threadIdx.x;
    cnt[tid] = 0; cnt[tid + 256] = 0;
    pos[tid] = 0; pos[tid + 256] = 0;
    __syncthreads();
    int nInt4 = (E + 3) >> 2;
    int i0 = blockIdx.x * 512 + tid;
    int i1 = i0 + 256;
    bool v0 = i0 < nInt4, v1 = i1 < nInt4;
    int4 s0 = make_int4(0,0,0,0), d0 = s0, s1 = s0, d1 = s0;
    if (v0) { s0 = src4[i0]; d0 = dst4[i0]; }
    if (v1) { s1 = src4[i1]; d1 = dst4[i1]; }
    int e0 = i0 << 2, e1 = i1 << 2;
    int ss[8] = {s0.x, s0.y, s0.z, s0.w, s1.x, s1.y, s1.z, s1.w};
    int dd[8] = {d0.x, d0.y, d0.z, d0.w, d1.x, d1.y, d1.z, d1.w};
    bool ok[8];
#pragma unroll
    for (int k = 0; k < 4; ++k) { ok[k] = v0 && (e0 + k < E); ok[4 + k] = v1 && (e1 + k < E); }
#pragma unroll
    for (int k = 0; k < 8; ++k) if (ok[k]) atomicAdd(&cnt[dd[k] >> SH], 1);
    __syncthreads();
    for (int b = tid; b < NB; b += 256)
        if (cnt[b] > 0) gbase[b] = atomicAdd(&gcnt[b], cnt[b]);
    __syncthreads();
    int pp[8];
#pragma unroll
    for (int k = 0; k < 8; ++k)
        pp[k] = ok[k] ? (gbase[dd[k] >> SH] + atomicAdd(&pos[dd[k] >> SH], 1)) : 0;
#pragma unroll
    for (int k = 0; k < 8; ++k) {
        if (!ok[k]) continue;
        int b = dd[k] >> SH;
        int pkt = (ss[k] << SH) | (dd[k] & (BNODES - 1));
        if (pp[k] < BCAP) buckets[(size_t)b * BCAP + pp[k]] = pkt;
        else { int o = atomicAdd(ovfCnt, 1); if (o < OVF_MAX) ovf[o] = make_int2(ss[k], dd[k]); }
    }
}

// ---------- pass 2 fused with gather: edge-parallel LDS accumulate + epilogue ----
// Block = bucket (256 nodes). acc layout: element e=4q+j of node l stored at
// acc[l*64 + ((q + 16j + l) & 63)]  -> bank-rotated, <=4-way conflicts.
__global__ __launch_bounds__(1024) void p2_gather(const int* __restrict__ buckets,
                                                  const int* __restrict__ gcnt,
                                                  const ushort4* __restrict__ msgb,
                                                  const float4* __restrict__ h4,
                                                  const float4* __restrict__ ini4,
                                                  const float* __restrict__ bef_A,
                                                  const float* __restrict__ bef_X,
                                                  float4* __restrict__ out4,
                                                  int N, int BCAP) {
    __shared__ float acc[BNODES * 64];   // 64 KB
    int b = blockIdx.x, tid = threadIdx.x;
    for (int k = tid; k < BNODES * 64; k += 1024) acc[k] = 0.f;
    __syncthreads();
    int nb = min(gcnt[b], BCAP);
    const int* bp = buckets + (size_t)b * BCAP;
    int grp = tid >> 4;          // 64 groups of 16 lanes
    int q = tid & 15;
    for (int i = grp; i < nb; i += 128) {
        int i2 = i + 64;
        bool has2 = i2 < nb;
        int pkt1 = bp[i];
        int pkt2 = has2 ? bp[i2] : pkt1;
        int l1 = pkt1 & (BNODES - 1);
        int s1v = (int)(((unsigned)pkt1) >> SH);
        int l2 = pkt2 & (BNODES - 1);
        int s2v = (int)(((unsigned)pkt2) >> SH);
        ushort4 m1 = msgb[(size_t)s1v * DV + q];
        ushort4 m2 = msgb[(size_t)s2v * DV + q];
        int base1 = l1 << 6;
        atomicAdd(&acc[base1 + ((q + 0  + l1) & 63)], b2f(m1.x));
        atomicAdd(&acc[base1 + ((q + 16 + l1) & 63)], b2f(m1.y));
        atomicAdd(&acc[base1 + ((q + 32 + l1) & 63)], b2f(m1.z));
        atomicAdd(&acc[base1 + ((q + 48 + l1) & 63)], b2f(m1.w));
        if (has2) {
            int base2 = l2 << 6;
            atomicAdd(&acc[base2 + ((q + 0  + l2) & 63)], b2f(m2.x));
            atomicAdd(&acc[base2 + ((q + 16 + l2) & 63)], b2f(m2.y));
            atomicAdd(&acc[base2 + ((q + 32 + l2) & 63)], b2f(m2.z));
            atomicAdd(&acc[base2 + ((q + 48 + l2) & 63)], b2f(m2.w));
        }
    }
    __syncthreads();
    // epilogue: 256 nodes x 16 float4 chunks, coalesced
    for (int idx = tid; idx < BNODES * 16; idx += 1024) {
        int l = idx >> 4, c = idx & 15;
        int g = (b << SH) + l;
        if (g >= N) break;
        int base = l << 6;
        float a0 = acc[base + ((c + 0  + l) & 63)];
        float a1 = acc[base + ((c + 16 + l) & 63)];
        float a2 = acc[base + ((c + 32 + l) & 63)];
        float a3 = acc[base + ((c + 48 + l) & 63)];
        float cb = ALP * bef_A[g];
        float bx = ALP * bef_X[g];
        size_t ridx = (size_t)g * DV + c;
        float4 hv = h4[ridx];
        float4 iv = ini4[ridx];
        float4 o;
        o.x = OMA * hv.x + bx * iv.x + cb * a0;
        o.y = OMA * hv.y + bx * iv.y + cb * a1;
        o.z = OMA * hv.z + bx * iv.z + cb * a2;
        o.w = OMA * hv.w + bx * iv.w + cb * a3;
        out4[ridx] = o;
    }
}

// ---------- overflow fixup (fp32 exact; runs after p2_gather) ----------
__global__ void vsgc_ovf(const float4* __restrict__ h4,
                         const float* __restrict__ aft_A,
                         const float* __restrict__ bef_A,
                         const int2* __restrict__ ovf,
                         const int* __restrict__ ovfCnt,
                         float* __restrict__ out) {
    int total = min(*ovfCnt, OVF_MAX);
    int stride = blockDim.x * gridDim.x;
    for (int t = blockIdx.x * blockDim.x + threadIdx.x; t < total * 16; t += stride) {
        int e = t >> 4, q = t & 15;
        int2 r = ovf[e];
        float c = ALP * aft_A[r.x] * bef_A[r.y];
        float4 hv = h4[(size_t)r.x * DV + q];
        float* op = out + (size_t)r.y * D + (q << 2);
        unsafeAtomicAdd(op + 0, c * hv.x);
        unsafeAtomicAdd(op + 1, c * hv.y);
        unsafeAtomicAdd(op + 2, c * hv.z);
        unsafeAtomicAdd(op + 3, c * hv.w);
    }
}

// ---------- last-resort fallback (R1 atomic path) ----------
__global__ void vsgc_init(const float4* __restrict__ h, const float4* __restrict__ ini_h,
                          const float* __restrict__ bef_X, float4* __restrict__ out, int n4) {
    int i = blockIdx.x * blockDim.x + threadIdx.x;
    if (i >= n4) return;
    int node = i >> 4;
    float bx = ALP * bef_X[node];
    float4 hv = h[i];
    float4 iv = ini_h[i];
    float4 o;
    o.x = OMA * hv.x + bx * iv.x;
    o.y = OMA * hv.y + bx * iv.y;
    o.z = OMA * hv.z + bx * iv.z;
    o.w = OMA * hv.w + bx * iv.w;
    out[i] = o;
}
__global__ void vsgc_edges_atomic(const float4* __restrict__ h,
                                  const float* __restrict__ aft_A,
                                  const float* __restrict__ bef_A,
                                  const int* __restrict__ src,
                                  const int* __restrict__ dst,
                                  float* __restrict__ out, int E) {
    int tid = blockIdx.x * blockDim.x + threadIdx.x;
    int e = tid >> 4;
    int q = tid & 15;
    if (e >= E) return;
    int s = src[e];
    int d = dst[e];
    float c = ALP * aft_A[s] * bef_A[d];
    float4 hv = h[(size_t)s * DV + q];
    float* op = out + (size_t)d * D + (q << 2);
    unsafeAtomicAdd(op + 0, c * hv.x);
    unsafeAtomicAdd(op + 1, c * hv.y);
    unsafeAtomicAdd(op + 2, c * hv.z);
    unsafeAtomicAdd(op + 3, c * hv.w);
}

extern "C" void kernel_launch(void* const* d_in, const int* in_sizes, int n_in,
                              void* d_out, int out_size, void* d_ws, size_t ws_size,
                              hipStream_t stream) {
    const float* h     = (const float*)d_in[0];
    const float* ini_h = (const float*)d_in[1];
    const float* bef_A = (const float*)d_in[2];
    const float* aft_A = (const float*)d_in[3];
    const float* bef_X = (const float*)d_in[4];
    const int*   src   = (const int*)d_in[5];
    const int*   dst   = (const int*)d_in[6];
    float* out = (float*)d_out;

    const int N = in_sizes[0] / D;      // 100000
    const int E = in_sizes[5];          // 800000
    const int t = 256;

    int NB = (N + BNODES - 1) >> SH;
    int perB = (NB > 0) ? E / NB : 0;
    int BCAP = ((perB + perB / 4 + 256) + 3) & ~3;

    // ws layout (256B aligned regions):
    // gcnt[512] | ovfCnt[64] | ovf int2[OVF_MAX] | buckets[NB*BCAP] | msgb ushort[N*64]
    size_t o_gcnt = 0;
    size_t o_ovfc = 512 * 4;
    size_t o_ovf  = ((o_ovfc + 64 * 4 + 255) / 256) * 256;
    size_t o_bkt  = o_ovf + (size_t)OVF_MAX * 8;
    size_t o_msg  = ((o_bkt + (size_t)NB * BCAP * 4 + 255) / 256) * 256;
    size_t need   = o_msg + (size_t)N * 128;

    if (NB <= 512 && N <= (1 << 23) && ws_size >= need) {
        int*  gcnt  = (int*)((char*)d_ws + o_gcnt);
        int*  ovfC  = (int*)((char*)d_ws + o_ovfc);
        int2* ovf   = (int2*)((char*)d_ws + o_ovf);
        int*  bkt   = (int*)((char*)d_ws + o_bkt);
        ushort4* msgb = (ushort4*)((char*)d_ws + o_msg);

        int zeroWords = (int)(o_ovf / 4);
        int n16 = N * DV;
        vsgc_msg<<<(n16 + t - 1) / t, t, 0, stream>>>(
            (const float4*)h, aft_A, msgb, (int*)d_ws, zeroWords, n16);

        int nInt4 = (E + 3) >> 2;
        int p1blocks = (nInt4 + 511) / 512;
        p1_scatter<<<p1blocks, 256, 0, stream>>>(
            (const int4*)src, (const int4*)dst, gcnt, bkt, ovf, ovfC, E, NB, BCAP);

        p2_gather<<<NB, 1024, 0, stream>>>(
            bkt, gcnt, msgb, (const float4*)h, (const float4*)ini_h,
            bef_A, bef_X, (float4*)out, N, BCAP);

        vsgc_ovf<<<32, t, 0, stream>>>((const float4*)h, aft_A, bef_A, ovf, ovfC, out);
    } else {
        int n4 = N * DV;
        vsgc_init<<<(n4 + t - 1) / t, t, 0, stream>>>(
            (const float4*)h, (const float4*)ini_h, bef_X, (float4*)out, n4);
        long long total = (long long)E * DV;
        vsgc_edges_atomic<<<(int)((total + t - 1) / t), t, 0, stream>>>(
            (const float4*)h, aft_A, bef_A, src, dst, out, E);
    }
}

// Round 10
// 162.281 us; speedup vs baseline: 2.8603x; 2.8603x over previous
//
#include <hip/hip_runtime.h>

#define ALP 0.1f          // alpha
#define OMA 0.9f          // 1 - alpha
#define D 64
#define DV 16             // float4 chunks per row
#define SH 9              // 512 nodes per bucket
#define NODES_PER_B 512
#define CAP 16            // ELL slots per node (deg>16 -> overflow fixup)
#define OVF_MAX 65536

// ---------- bf16 helpers ----------
__device__ __forceinline__ unsigned short f2b(float f) {      // RNE
    unsigned u = __float_as_uint(f);
    unsigned r = u + 0x7fffu + ((u >> 16) & 1u);
    return (unsigned short)(r >> 16);
}
__device__ __forceinline__ float b2f(unsigned short u) {
    return __uint_as_float(((unsigned)u) << 16);
}

// ---------- merged: p1 bucket scatter (blocks < p1Blocks) + msg convert ----------
__global__ __launch_bounds__(256) void vsgc_msgp1(
        const float4* __restrict__ h4, const float* __restrict__ aft_A,
        ushort4* __restrict__ msgb, int n16,
        const int4* __restrict__ src4, const int4* __restrict__ dst4,
        int* __restrict__ gcnt, int* __restrict__ buckets,
        int2* __restrict__ ovf, int* __restrict__ ovfCnt,
        int E, int NB, int BCAP, int p1Blocks) {
    int tid = threadIdx.x;
    if ((int)blockIdx.x >= p1Blocks) {
        // ---- msg role: msgb[i] = bf16(h[i] * aft_A[node]) ----
        int i = (blockIdx.x - p1Blocks) * 256 + tid;
        if (i < n16) {
            float w = aft_A[i >> 4];
            float4 v = h4[i];
            msgb[i] = make_ushort4(f2b(v.x * w), f2b(v.y * w), f2b(v.z * w), f2b(v.w * w));
        }
        return;
    }
    // ---- p1 role: packed 4B records (src<<SH | local_dst), phase-split ----
    __shared__ int cnt[256], gbase[256], pos[256];
    cnt[tid] = 0; pos[tid] = 0;
    __syncthreads();
    int nInt4 = (E + 3) >> 2;
    int i0 = blockIdx.x * 512 + tid;
    int i1 = i0 + 256;
    bool v0 = i0 < nInt4, v1 = i1 < nInt4;
    int4 s0 = make_int4(0,0,0,0), d0 = s0, s1 = s0, d1 = s0;
    if (v0) { s0 = src4[i0]; d0 = dst4[i0]; }
    if (v1) { s1 = src4[i1]; d1 = dst4[i1]; }
    int e0 = i0 << 2, e1 = i1 << 2;
    int ss[8] = {s0.x, s0.y, s0.z, s0.w, s1.x, s1.y, s1.z, s1.w};
    int dd[8] = {d0.x, d0.y, d0.z, d0.w, d1.x, d1.y, d1.z, d1.w};
    bool ok[8];
#pragma unroll
    for (int k = 0; k < 4; ++k) { ok[k] = v0 && (e0 + k < E); ok[4 + k] = v1 && (e1 + k < E); }
#pragma unroll
    for (int k = 0; k < 8; ++k) if (ok[k]) atomicAdd(&cnt[dd[k] >> SH], 1);
    __syncthreads();
    if (tid < NB && cnt[tid] > 0) gbase[tid] = atomicAdd(&gcnt[tid], cnt[tid]);
    __syncthreads();
    int pp[8];
#pragma unroll
    for (int k = 0; k < 8; ++k)
        pp[k] = ok[k] ? (gbase[dd[k] >> SH] + atomicAdd(&pos[dd[k] >> SH], 1)) : 0;
#pragma unroll
    for (int k = 0; k < 8; ++k) {
        if (!ok[k]) continue;
        int b = dd[k] >> SH;
        int pkt = (ss[k] << SH) | (dd[k] & (NODES_PER_B - 1));
        if (pp[k] < BCAP) buckets[(size_t)b * BCAP + pp[k]] = pkt;
        else { int o = atomicAdd(ovfCnt, 1); if (o < OVF_MAX) ovf[o] = make_int2(ss[k], dd[k]); }
    }
}

// ---------- pass 2: bucket records -> node-local ELL (int4 reads) ----------
__global__ __launch_bounds__(512) void p2_ell(const int* __restrict__ buckets,
                                              const int* __restrict__ gcnt,
                                              int* __restrict__ ell,
                                              int* __restrict__ cnt_g,
                                              int2* __restrict__ ovf,
                                              int* __restrict__ ovfCnt,
                                              int N, int BCAP) {
    __shared__ int npos[NODES_PER_B];
    int b = blockIdx.x, tid = threadIdx.x;
    npos[tid] = 0;
    __syncthreads();
    int nb = min(gcnt[b], BCAP);
    const int4* bp4 = (const int4*)(buckets + (size_t)b * BCAP);
    int nIter = (nb + 3) >> 2;
    for (int i4 = tid; i4 < nIter; i4 += 512) {
        int4 r4 = bp4[i4];
        int base = i4 << 2;
        int pk[4] = {r4.x, r4.y, r4.z, r4.w};
#pragma unroll
        for (int k = 0; k < 4; ++k) {
            if (base + k >= nb) break;
            int pkt = pk[k];
            int l = pkt & (NODES_PER_B - 1);
            int s = (int)(((unsigned)pkt) >> SH);
            int slot = atomicAdd(&npos[l], 1);
            int node = (b << SH) + l;
            if (slot < CAP) ell[(size_t)node * CAP + slot] = s;
            else { int o = atomicAdd(ovfCnt, 1); if (o < OVF_MAX) ovf[o] = make_int2(s, node); }
        }
    }
    __syncthreads();
    int node = (b << SH) + tid;
    if (node < N) cnt_g[node] = npos[tid];
}

// ---------- gather: 2 nodes per wave, static ELL addresses ----------
__global__ __launch_bounds__(256) void vsgc_gather_ell(const ushort4* __restrict__ msgb,
                                                       const float4* __restrict__ h4,
                                                       const float4* __restrict__ ini4,
                                                       const float* __restrict__ bef_A,
                                                       const float* __restrict__ bef_X,
                                                       const int* __restrict__ cnt_g,
                                                       const int* __restrict__ ell,
                                                       float4* __restrict__ out4, int N) {
    int wid = (blockIdx.x * blockDim.x + threadIdx.x) >> 6;
    int g0 = wid * 2;
    if (g0 >= N) return;
    int g1 = g0 + 1;
    bool has1 = g1 < N;
    int g1c = has1 ? g1 : g0;
    int lane = threadIdx.x & 63;
    int w = lane >> 4;          // group 0..3
    int q = lane & 15;
    size_t r0 = (size_t)g0 * DV + q;
    size_t r1 = (size_t)g1c * DV + q;
    // all independent loads issued up front
    int ev0 = ell[(size_t)g0 * CAP + q];
    int ev1 = ell[(size_t)g1c * CAP + q];
    int n0 = min(cnt_g[g0], CAP);
    int n1 = has1 ? min(cnt_g[g1c], CAP) : 0;
    float4 hv0 = h4[r0];
    float4 hv1 = h4[r1];
    float4 iv0 = ini4[r0];
    float4 iv1 = ini4[r1];
    float cb0 = ALP * bef_A[g0];
    float bx0 = ALP * bef_X[g0];
    float cb1 = ALP * bef_A[g1c];
    float bx1 = ALP * bef_X[g1c];
    float4 a0 = make_float4(0.f, 0.f, 0.f, 0.f);
    float4 a1 = a0;
    unsigned clampN = (unsigned)(N - 1);
#pragma unroll
    for (int k = 0; k < 4; ++k) {
        int idx = w + 4 * k;
        int s0 = __shfl(ev0, idx);
        int s1 = __shfl(ev1, idx);
        unsigned su0 = min((unsigned)s0, clampN);
        unsigned su1 = min((unsigned)s1, clampN);
        float m0 = (idx < n0) ? 1.f : 0.f;
        float m1 = (idx < n1) ? 1.f : 0.f;
        ushort4 q0 = msgb[(size_t)su0 * DV + q];
        ushort4 q1 = msgb[(size_t)su1 * DV + q];
        a0.x += m0 * b2f(q0.x); a0.y += m0 * b2f(q0.y);
        a0.z += m0 * b2f(q0.z); a0.w += m0 * b2f(q0.w);
        a1.x += m1 * b2f(q1.x); a1.y += m1 * b2f(q1.y);
        a1.z += m1 * b2f(q1.z); a1.w += m1 * b2f(q1.w);
    }
    a0.x += __shfl_xor(a0.x, 16); a0.y += __shfl_xor(a0.y, 16);
    a0.z += __shfl_xor(a0.z, 16); a0.w += __shfl_xor(a0.w, 16);
    a0.x += __shfl_xor(a0.x, 32); a0.y += __shfl_xor(a0.y, 32);
    a0.z += __shfl_xor(a0.z, 32); a0.w += __shfl_xor(a0.w, 32);
    a1.x += __shfl_xor(a1.x, 16); a1.y += __shfl_xor(a1.y, 16);
    a1.z += __shfl_xor(a1.z, 16); a1.w += __shfl_xor(a1.w, 16);
    a1.x += __shfl_xor(a1.x, 32); a1.y += __shfl_xor(a1.y, 32);
    a1.z += __shfl_xor(a1.z, 32); a1.w += __shfl_xor(a1.w, 32);
    // w==0 lanes write node g0, w==1 lanes write node g1
    if (w == 0) {
        float4 o;
        o.x = OMA * hv0.x + bx0 * iv0.x + cb0 * a0.x;
        o.y = OMA * hv0.y + bx0 * iv0.y + cb0 * a0.y;
        o.z = OMA * hv0.z + bx0 * iv0.z + cb0 * a0.z;
        o.w = OMA * hv0.w + bx0 * iv0.w + cb0 * a0.w;
        out4[r0] = o;
    } else if (w == 1 && has1) {
        float4 o;
        o.x = OMA * hv1.x + bx1 * iv1.x + cb1 * a1.x;
        o.y = OMA * hv1.y + bx1 * iv1.y + cb1 * a1.y;
        o.z = OMA * hv1.z + bx1 * iv1.z + cb1 * a1.z;
        o.w = OMA * hv1.w + bx1 * iv1.w + cb1 * a1.w;
        out4[r1] = o;
    }
}

// ---------- overflow fixup (fp32 exact) ----------
__global__ void vsgc_ovf(const float4* __restrict__ h4,
                         const float* __restrict__ aft_A,
                         const float* __restrict__ bef_A,
                         const int2* __restrict__ ovf,
                         const int* __restrict__ ovfCnt,
                         float* __restrict__ out) {
    int total = min(*ovfCnt, OVF_MAX);
    int stride = blockDim.x * gridDim.x;
    for (int t = blockIdx.x * blockDim.x + threadIdx.x; t < total * 16; t += stride) {
        int e = t >> 4, q = t & 15;
        int2 r = ovf[e];
        float c = ALP * aft_A[r.x] * bef_A[r.y];
        float4 hv = h4[(size_t)r.x * DV + q];
        float* op = out + (size_t)r.y * D + (q << 2);
        unsafeAtomicAdd(op + 0, c * hv.x);
        unsafeAtomicAdd(op + 1, c * hv.y);
        unsafeAtomicAdd(op + 2, c * hv.z);
        unsafeAtomicAdd(op + 3, c * hv.w);
    }
}

// ---------- last-resort fallback (R1 atomic path) ----------
__global__ void vsgc_init(const float4* __restrict__ h, const float4* __restrict__ ini_h,
                          const float* __restrict__ bef_X, float4* __restrict__ out, int n4) {
    int i = blockIdx.x * blockDim.x + threadIdx.x;
    if (i >= n4) return;
    int node = i >> 4;
    float bx = ALP * bef_X[node];
    float4 hv = h[i];
    float4 iv = ini_h[i];
    float4 o;
    o.x = OMA * hv.x + bx * iv.x;
    o.y = OMA * hv.y + bx * iv.y;
    o.z = OMA * hv.z + bx * iv.z;
    o.w = OMA * hv.w + bx * iv.w;
    out[i] = o;
}
__global__ void vsgc_edges_atomic(const float4* __restrict__ h,
                                  const float* __restrict__ aft_A,
                                  const float* __restrict__ bef_A,
                                  const int* __restrict__ src,
                                  const int* __restrict__ dst,
                                  float* __restrict__ out, int E) {
    int tid = blockIdx.x * blockDim.x + threadIdx.x;
    int e = tid >> 4;
    int q = tid & 15;
    if (e >= E) return;
    int s = src[e];
    int d = dst[e];
    float c = ALP * aft_A[s] * bef_A[d];
    float4 hv = h[(size_t)s * DV + q];
    float* op = out + (size_t)d * D + (q << 2);
    unsafeAtomicAdd(op + 0, c * hv.x);
    unsafeAtomicAdd(op + 1, c * hv.y);
    unsafeAtomicAdd(op + 2, c * hv.z);
    unsafeAtomicAdd(op + 3, c * hv.w);
}

extern "C" void kernel_launch(void* const* d_in, const int* in_sizes, int n_in,
                              void* d_out, int out_size, void* d_ws, size_t ws_size,
                              hipStream_t stream) {
    const float* h     = (const float*)d_in[0];
    const float* ini_h = (const float*)d_in[1];
    const float* bef_A = (const float*)d_in[2];
    const float* aft_A = (const float*)d_in[3];
    const float* bef_X = (const float*)d_in[4];
    const int*   src   = (const int*)d_in[5];
    const int*   dst   = (const int*)d_in[6];
    float* out = (float*)d_out;

    const int N = in_sizes[0] / D;      // 100000
    const int E = in_sizes[5];          // 800000
    const int t = 256;

    int NB = (N + NODES_PER_B - 1) >> SH;
    int perB = (NB > 0) ? E / NB : 0;
    int BCAP = ((perB + perB / 4 + 256) + 3) & ~3;   // int4-aligned

    // ws layout (256B aligned regions):
    // gcnt[256] | ovfCnt[64] | ovf int2[OVF_MAX] | cnt_g[N] | ell[N*CAP]
    // | buckets[NB*BCAP] | msgb ushort[N*64]
    size_t o_gcnt = 0;
    size_t o_ovfc = 256 * 4;
    size_t o_ovf  = ((o_ovfc + 64 * 4 + 255) / 256) * 256;
    size_t o_cnt  = o_ovf + (size_t)OVF_MAX * 8;
    size_t o_ell  = ((o_cnt + (size_t)N * 4 + 255) / 256) * 256;
    size_t o_bkt  = ((o_ell + (size_t)N * CAP * 4 + 255) / 256) * 256;
    size_t o_msg  = ((o_bkt + (size_t)NB * BCAP * 4 + 255) / 256) * 256;
    size_t need   = o_msg + (size_t)N * 128;

    if (NB <= 256 && N <= (1 << (31 - SH)) && ws_size >= need) {
        int*  gcnt  = (int*)((char*)d_ws + o_gcnt);
        int*  ovfC  = (int*)((char*)d_ws + o_ovfc);
        int2* ovf   = (int2*)((char*)d_ws + o_ovf);
        int*  cnt_g = (int*)((char*)d_ws + o_cnt);
        int*  ell   = (int*)((char*)d_ws + o_ell);
        int*  bkt   = (int*)((char*)d_ws + o_bkt);
        ushort4* msgb = (ushort4*)((char*)d_ws + o_msg);

        hipMemsetAsync(d_ws, 0, o_ovf, stream);   // gcnt + ovfCnt (tiny)

        int n16 = N * DV;
        int nInt4 = (E + 3) >> 2;
        int p1Blocks = (nInt4 + 511) / 512;
        int msgBlocks = (n16 + t - 1) / t;
        vsgc_msgp1<<<p1Blocks + msgBlocks, t, 0, stream>>>(
            (const float4*)h, aft_A, msgb, n16,
            (const int4*)src, (const int4*)dst, gcnt, bkt, ovf, ovfC,
            E, NB, BCAP, p1Blocks);

        p2_ell<<<NB, 512, 0, stream>>>(bkt, gcnt, ell, cnt_g, ovf, ovfC, N, BCAP);

        long long waves = (N + 1) / 2;
        long long threadsTotal = waves * 64;
        vsgc_gather_ell<<<(int)((threadsTotal + t - 1) / t), t, 0, stream>>>(
            msgb, (const float4*)h, (const float4*)ini_h, bef_A, bef_X,
            cnt_g, ell, (float4*)out, N);

        vsgc_ovf<<<32, t, 0, stream>>>((const float4*)h, aft_A, bef_A, ovf, ovfC, out);
    } else {
        int n4 = N * DV;
        vsgc_init<<<(n4 + t - 1) / t, t, 0, stream>>>(
            (const float4*)h, (const float4*)ini_h, bef_X, (float4*)out, n4);
        long long total = (long long)E * DV;
        vsgc_edges_atomic<<<(int)((total + t - 1) / t), t, 0, stream>>>(
            (const float4*)h, aft_A, bef_A, src, dst, out, E);
    }
}